// Round 2
// baseline (763.327 us; speedup 1.0000x reference)
//
#include <hip/hip_runtime.h>

#define B_ALL 4096
#define NWIN  64
#define NTOK  49
#define DIMC  128
#define NH    4
#define HD    32
#define SCALE 0.17677669529663687f  // 32^-0.5

// out = A(M x 128) @ W(N x 128)^T + bias
// MODE 0: N=384 (grid.y=3), scatter to qkv ws (3, Bsl, 4, 49, 32), q *= SCALE
// MODE 1: N=128 (grid.y=1), plain write out[m*128 + c]
template<int MODE>
__global__ __launch_bounds__(256, 4)
void gemm_k(const float* __restrict__ A, const float* __restrict__ W,
            const float* __restrict__ bias, float* __restrict__ out,
            int M, int Bsl) {
  __shared__ float As[32][132];   // [k][m], pad 132: staging 4-way, reads conflict-free
  __shared__ float Bs[32][132];   // [k][n]
  const int tid = threadIdx.x;
  const int tx = tid & 15, ty = tid >> 4;
  const int mblk = blockIdx.x * 128;
  const int nblk = blockIdx.y * 128;

  float acc[8][8];
#pragma unroll
  for (int i = 0; i < 8; ++i)
#pragma unroll
    for (int j = 0; j < 8; ++j) acc[i][j] = 0.f;

  for (int kt = 0; kt < 128; kt += 32) {
#pragma unroll
    for (int t = 0; t < 4; ++t) {
      int fidx = tid + t * 256;          // 1024 float4 total per operand
      int ml = fidx >> 3, k4 = fidx & 7; // 128 rows x 8 float4
      int m = mblk + ml;
      float4 v = make_float4(0.f, 0.f, 0.f, 0.f);
      if (m < M) v = *(const float4*)(A + (size_t)m * DIMC + kt + k4 * 4);
      As[k4 * 4 + 0][ml] = v.x; As[k4 * 4 + 1][ml] = v.y;
      As[k4 * 4 + 2][ml] = v.z; As[k4 * 4 + 3][ml] = v.w;
      int n = nblk + ml;                 // N is multiple of 128 in both modes
      float4 w4 = *(const float4*)(W + (size_t)n * DIMC + kt + k4 * 4);
      Bs[k4 * 4 + 0][ml] = w4.x; Bs[k4 * 4 + 1][ml] = w4.y;
      Bs[k4 * 4 + 2][ml] = w4.z; Bs[k4 * 4 + 3][ml] = w4.w;
    }
    __syncthreads();
#pragma unroll 8
    for (int kk = 0; kk < 32; ++kk) {
      float a[8], b[8];
#pragma unroll
      for (int i = 0; i < 8; ++i) a[i] = As[kk][ty * 8 + i];
#pragma unroll
      for (int j = 0; j < 8; ++j) b[j] = Bs[kk][tx + 16 * j];
#pragma unroll
      for (int i = 0; i < 8; ++i)
#pragma unroll
        for (int j = 0; j < 8; ++j) acc[i][j] = fmaf(a[i], b[j], acc[i][j]);
    }
    __syncthreads();
  }

  float bv[8];
#pragma unroll
  for (int j = 0; j < 8; ++j) bv[j] = bias[nblk + tx + 16 * j];

#pragma unroll
  for (int i = 0; i < 8; ++i) {
    int m = mblk + ty * 8 + i;
    if (m >= M) continue;
    int bw = m / NTOK;
    int r  = m - bw * NTOK;
#pragma unroll
    for (int j = 0; j < 8; ++j) {
      int c = nblk + tx + 16 * j;
      float v = acc[i][j] + bv[j];
      if (MODE == 0) {
        int s = c >> 7, h = (c >> 5) & 3, d = c & 31;
        if (s == 0) v *= SCALE;
        out[((((size_t)s * Bsl + bw) * NH + h) * NTOK + r) * HD + d] = v;
      } else {
        out[(size_t)m * DIMC + c] = v;
      }
    }
  }
}

// One block per window, wave h handles head h. Lane l owns query row l (l<49).
__global__ __launch_bounds__(256, 2)
void attn_k(const float* __restrict__ qkv, const float* __restrict__ mask,
            const float* __restrict__ bias_table, const int* __restrict__ rel_index,
            float* __restrict__ attn_out, int Bsl, int win0) {
  __shared__ float kv[NH][NTOK * HD];      // 4 x 1568 f32 (K, then reused for V)
  __shared__ float bs[NH * NTOK * NTOK];   // merged rel-bias + window mask
  const int tid = threadIdx.x;
  const int h = tid >> 6, l = tid & 63;
  const int b = blockIdx.x;
  const int wi = (win0 + b) & (NWIN - 1);

  for (int idx = tid; idx < NH * NTOK * NTOK; idx += 256) {
    int h2 = idx / (NTOK * NTOK);
    int ij = idx - h2 * (NTOK * NTOK);
    bs[idx] = bias_table[rel_index[ij] * NH + h2] + mask[wi * (NTOK * NTOK) + ij];
  }
  const float4* Kh = (const float4*)(qkv + (((size_t)Bsl + b) * NH + h) * (NTOK * HD));
  float4* kvh4 = (float4*)&kv[h][0];
  for (int i = l; i < NTOK * HD / 4; i += 64) kvh4[i] = Kh[i];
  __syncthreads();

  float q[HD];
  const float* Qh = qkv + ((size_t)b * NH + h) * (NTOK * HD) + l * HD;
  if (l < NTOK) {
#pragma unroll
    for (int d4 = 0; d4 < HD / 4; ++d4) {
      float4 t = ((const float4*)Qh)[d4];
      q[d4 * 4 + 0] = t.x; q[d4 * 4 + 1] = t.y;
      q[d4 * 4 + 2] = t.z; q[d4 * 4 + 3] = t.w;
    }
  }

  float lg[NTOK];
  if (l < NTOK) {
#pragma unroll
    for (int j = 0; j < NTOK; ++j) {
      float s = bs[h * (NTOK * NTOK) + l * NTOK + j];
#pragma unroll
      for (int d = 0; d < HD; ++d) s = fmaf(q[d], kv[h][j * HD + d], s);
      lg[j] = s;
    }
  }

  // V overwrites this wave's private K region; DS ops are in-order per wave.
  const float4* Vh = (const float4*)(qkv + (((size_t)2 * Bsl + b) * NH + h) * (NTOK * HD));
  for (int i = l; i < NTOK * HD / 4; i += 64) kvh4[i] = Vh[i];

  if (l < NTOK) {
    float mx = lg[0];
#pragma unroll
    for (int j = 1; j < NTOK; ++j) mx = fmaxf(mx, lg[j]);
    float sum = 0.f;
#pragma unroll
    for (int j = 0; j < NTOK; ++j) { float p = __expf(lg[j] - mx); lg[j] = p; sum += p; }
    float inv = 1.f / sum;

    float o[HD];
#pragma unroll
    for (int d = 0; d < HD; ++d) o[d] = 0.f;
#pragma unroll
    for (int j = 0; j < NTOK; ++j) {
      float p = lg[j];
#pragma unroll
      for (int d = 0; d < HD; ++d) o[d] = fmaf(p, kv[h][j * HD + d], o[d]);
    }
    float* O = attn_out + ((size_t)b * NTOK + l) * DIMC + h * HD;
#pragma unroll
    for (int d4 = 0; d4 < HD / 4; ++d4) {
      ((float4*)O)[d4] = make_float4(o[d4 * 4 + 0] * inv, o[d4 * 4 + 1] * inv,
                                     o[d4 * 4 + 2] * inv, o[d4 * 4 + 3] * inv);
    }
  }
}

extern "C" void kernel_launch(void* const* d_in, const int* in_sizes, int n_in,
                              void* d_out, int out_size, void* d_ws, size_t ws_size,
                              hipStream_t stream) {
  const float* x          = (const float*)d_in[0];
  const float* mask       = (const float*)d_in[1];
  const float* qkv_w      = (const float*)d_in[2];
  const float* qkv_b      = (const float*)d_in[3];
  const float* proj_w     = (const float*)d_in[4];
  const float* proj_b     = (const float*)d_in[5];
  const float* bias_table = (const float*)d_in[6];
  const int*   rel_index  = (const int*)d_in[7];
  float* out = (float*)d_out;

  // Per-window ws need: qkv 3*4*49*32 + attn_out 49*128 = 25088 f32 = 100352 B.
  // Slice the batch if ws_size is small (deterministic in ws_size -> same work per call).
  int NC = 1;
  while (NC < 64 && (size_t)(B_ALL / NC) * 100352ull > ws_size) NC <<= 1;
  const int Bsl = B_ALL / NC;
  const int Msl = Bsl * NTOK;

  float* qkv_ws  = (float*)d_ws;                                  // (3,Bsl,4,49,32)
  float* attn_ws = qkv_ws + (size_t)3 * Bsl * NH * NTOK * HD;     // (Bsl,49,128)

  for (int sl = 0; sl < NC; ++sl) {
    const float* xs = x + (size_t)sl * Bsl * NTOK * DIMC;
    dim3 g1((Msl + 127) / 128, 3);
    gemm_k<0><<<g1, 256, 0, stream>>>(xs, qkv_w, qkv_b, qkv_ws, Msl, Bsl);
    attn_k<<<dim3(Bsl), 256, 0, stream>>>(qkv_ws, mask, bias_table, rel_index,
                                          attn_ws, Bsl, sl * Bsl);
    dim3 g3((Msl + 127) / 128, 1);
    gemm_k<1><<<g3, 256, 0, stream>>>(attn_ws, proj_w, proj_b,
                                      out + (size_t)sl * Bsl * NTOK * DIMC, Msl, Bsl);
  }
}

// Round 5
// 694.681 us; speedup vs baseline: 1.0988x; 1.0988x over previous
//
#include <hip/hip_runtime.h>

#define B_ALL 4096
#define NWIN  64
#define NTOK  49
#define DIMC  128
#define NH    4
#define HD    32
#define SCALE 0.17677669529663687f  // 32^-0.5

typedef __attribute__((ext_vector_type(8))) __bf16 bf16x8;
typedef __attribute__((ext_vector_type(4))) float f32x4;

// ws layout (bytes):
//   [0,       98304)   qw_hi  (384*128 bf16)
//   [98304,  196608)   qw_lo
//   [196608, 229376)   pw_hi  (128*128 bf16)
//   [229376, 262144)   pw_lo
//   [262144, 2720768)  bmT    (64*4*49*49 f32, [wi][h][j][i] j-major)
//   [2720768, ...)     qkv_ws (3,Bsl,4,49,32 f32) then attn_ws (Bsl,49,128 f32)

__global__ void wpack_k(const float* __restrict__ qkv_w, const float* __restrict__ proj_w,
                        __bf16* __restrict__ dst) {
  int idx = blockIdx.x * 256 + threadIdx.x;       // 65536 total
  float w;
  __bf16 *hi, *lo;
  if (idx < 49152) { w = qkv_w[idx]; hi = dst; lo = dst + 49152; }
  else { idx -= 49152; w = proj_w[idx]; hi = dst + 98304; lo = dst + 98304 + 16384; }
  __bf16 h = (__bf16)w;
  hi[idx] = h;
  lo[idx] = (__bf16)(w - (float)h);
}

__global__ void bm_k(const float* __restrict__ mask, const float* __restrict__ bias_table,
                     const int* __restrict__ rel_index, float* __restrict__ bmT) {
  int idx = blockIdx.x * 256 + threadIdx.x;       // 64*4*49*49 = 614656 (exact grid)
  int i = idx % NTOK;
  int t = idx / NTOK;
  int j = t % NTOK; t /= NTOK;
  int h = t % NH;
  int wi = t / NH;
  bmT[idx] = bias_table[rel_index[i * NTOK + j] * NH + h] + mask[wi * (NTOK * NTOK) + i * NTOK + j];
}

// C = A(Mx128) @ W(Nx128)^T + bias via split-bf16 3-term MFMA.
// MODE 0: N=384, scatter to qkv ws (3,Bsl,4,49,32), q *= SCALE
// MODE 1: N=128, out[m*128+c]
template<int MODE>
__global__ __launch_bounds__(256)
void mgemm_k(const float* __restrict__ A, const __bf16* __restrict__ Wh,
             const __bf16* __restrict__ Wl, const float* __restrict__ bias,
             float* __restrict__ out, int M, int Bsl) {
  // 40-col stride (80 B): frag-read banks = row*20+kg*4 mod 32, period 8 -> ~2-way (free)
  __shared__ __bf16 Ah[128][40], Al[128][40], Bh[128][40], Bl[128][40];
  const int tid  = threadIdx.x;
  const int lane = tid & 63, wid = tid >> 6;
  const int wrow = wid >> 1, wcol = wid & 1;           // 2x2 waves of 64x64
  const int mblk = blockIdx.x * 128, nblk = blockIdx.y * 128;
  const int srow = tid >> 1, skh = (tid & 1) * 16;     // staging: 16 k per thread
  const int lrow = lane & 15, lk = (lane >> 4) * 8;    // fragment row/k-base

  f32x4 acc[4][4];
#pragma unroll
  for (int i = 0; i < 4; ++i)
#pragma unroll
    for (int j = 0; j < 4; ++j) acc[i][j] = (f32x4){0.f, 0.f, 0.f, 0.f};

  for (int kt = 0; kt < 128; kt += 32) {
    // ---- stage A (fp32 -> hi/lo bf16) ----
    {
      float f[16];
      int m = mblk + srow;
      if (m < M) {
        const float4* Ap = (const float4*)(A + (size_t)m * DIMC + kt + skh);
#pragma unroll
        for (int q = 0; q < 4; ++q) {
          float4 v = Ap[q];
          f[4 * q + 0] = v.x; f[4 * q + 1] = v.y; f[4 * q + 2] = v.z; f[4 * q + 3] = v.w;
        }
      } else {
#pragma unroll
        for (int e = 0; e < 16; ++e) f[e] = 0.f;
      }
      bf16x8 h0, h1, l0, l1;
#pragma unroll
      for (int e = 0; e < 8; ++e) {
        __bf16 h = (__bf16)f[e];     h0[e] = h; l0[e] = (__bf16)(f[e] - (float)h);
        __bf16 g = (__bf16)f[e + 8]; h1[e] = g; l1[e] = (__bf16)(f[e + 8] - (float)g);
      }
      *(bf16x8*)&Ah[srow][skh] = h0; *(bf16x8*)&Ah[srow][skh + 8] = h1;
      *(bf16x8*)&Al[srow][skh] = l0; *(bf16x8*)&Al[srow][skh + 8] = l1;
      // ---- stage B (prepacked bf16 hi/lo), n = nblk+srow always < N ----
      const bf16x8* Whp = (const bf16x8*)(Wh + (size_t)(nblk + srow) * DIMC + kt + skh);
      const bf16x8* Wlp = (const bf16x8*)(Wl + (size_t)(nblk + srow) * DIMC + kt + skh);
      *(bf16x8*)&Bh[srow][skh] = Whp[0]; *(bf16x8*)&Bh[srow][skh + 8] = Whp[1];
      *(bf16x8*)&Bl[srow][skh] = Wlp[0]; *(bf16x8*)&Bl[srow][skh + 8] = Wlp[1];
    }
    __syncthreads();

    bf16x8 afh[4], afl[4];
#pragma unroll
    for (int mt = 0; mt < 4; ++mt) {
      afh[mt] = *(const bf16x8*)&Ah[wrow * 64 + mt * 16 + lrow][lk];
      afl[mt] = *(const bf16x8*)&Al[wrow * 64 + mt * 16 + lrow][lk];
    }
#pragma unroll
    for (int nt = 0; nt < 4; ++nt) {
      bf16x8 bh = *(const bf16x8*)&Bh[wcol * 64 + nt * 16 + lrow][lk];
      bf16x8 bl = *(const bf16x8*)&Bl[wcol * 64 + nt * 16 + lrow][lk];
#pragma unroll
      for (int mt = 0; mt < 4; ++mt) {
        acc[mt][nt] = __builtin_amdgcn_mfma_f32_16x16x32_bf16(afh[mt], bh, acc[mt][nt], 0, 0, 0);
        acc[mt][nt] = __builtin_amdgcn_mfma_f32_16x16x32_bf16(afh[mt], bl, acc[mt][nt], 0, 0, 0);
        acc[mt][nt] = __builtin_amdgcn_mfma_f32_16x16x32_bf16(afl[mt], bh, acc[mt][nt], 0, 0, 0);
      }
    }
    __syncthreads();
  }

  // ---- epilogue: C/D layout col = lane&15, row = (lane>>4)*4 + r ----
#pragma unroll
  for (int nt = 0; nt < 4; ++nt) {
    int c = nblk + wcol * 64 + nt * 16 + lrow;
    float bv = bias[c];
#pragma unroll
    for (int mt = 0; mt < 4; ++mt) {
#pragma unroll
      for (int r = 0; r < 4; ++r) {
        int m = mblk + wrow * 64 + mt * 16 + (lane >> 4) * 4 + r;
        if (m >= M) continue;
        float v = acc[mt][nt][r] + bv;
        if (MODE == 0) {
          int s = c >> 7, hh = (c >> 5) & 3, d = c & 31;
          if (s == 0) v *= SCALE;
          int bw = m / NTOK, rr = m - bw * NTOK;
          out[((((size_t)s * Bsl + bw) * NH + hh) * NTOK + rr) * HD + d] = v;
        } else {
          out[(size_t)m * DIMC + c] = v;
        }
      }
    }
  }
}

// Block = 1 window, wave h = head h, lane l = query row (l<49). Barrier-free:
// each wave touches only kv[h]; same-wave DS ops are in-order.
__global__ __launch_bounds__(256, 4)
void attn_k2(const float* __restrict__ qkv, const float* __restrict__ bmT,
             float* __restrict__ attn_out, int Bsl, int win0) {
  __shared__ float kv[NH][NTOK * HD];   // K, then overwritten by V
  const int tid = threadIdx.x;
  const int h = tid >> 6, l = tid & 63;
  const int b = blockIdx.x;
  const int wi = (win0 + b) & (NWIN - 1);

  // stage K for this head
  const float4* Kh = (const float4*)(qkv + (((size_t)Bsl + b) * NH + h) * (NTOK * HD));
  float4* kvh4 = (float4*)&kv[h][0];
  for (int i = l; i < NTOK * HD / 4; i += 64) kvh4[i] = Kh[i];

  float q[HD];
  const float* Qh = qkv + ((size_t)b * NH + h) * (NTOK * HD) + l * HD;
  if (l < NTOK) {
#pragma unroll
    for (int d4 = 0; d4 < HD / 4; ++d4) {
      float4 t = ((const float4*)Qh)[d4];
      q[d4 * 4 + 0] = t.x; q[d4 * 4 + 1] = t.y; q[d4 * 4 + 2] = t.z; q[d4 * 4 + 3] = t.w;
    }
  }

  const float* bmh = bmT + ((size_t)wi * NH + h) * (NTOK * NTOK);  // [j][i]
  float lg[NTOK];
  if (l < NTOK) {
#pragma unroll
    for (int j = 0; j < NTOK; ++j) {
      float s = bmh[j * NTOK + l];      // coalesced over lanes (L3-resident)
#pragma unroll
      for (int d4 = 0; d4 < HD / 4; ++d4) {
        float4 kvec = ((const float4*)&kv[h][j * HD])[d4];
        s = fmaf(q[d4 * 4 + 0], kvec.x, s);
        s = fmaf(q[d4 * 4 + 1], kvec.y, s);
        s = fmaf(q[d4 * 4 + 2], kvec.z, s);
        s = fmaf(q[d4 * 4 + 3], kvec.w, s);
      }
      lg[j] = s;
    }
  }

  // V overwrites this wave's K region (in-order per wave, after the lg reads above)
  const float4* Vh = (const float4*)(qkv + (((size_t)2 * Bsl + b) * NH + h) * (NTOK * HD));
  for (int i = l; i < NTOK * HD / 4; i += 64) kvh4[i] = Vh[i];

  if (l < NTOK) {
    float mx = lg[0];
#pragma unroll
    for (int j = 1; j < NTOK; ++j) mx = fmaxf(mx, lg[j]);
    float sum = 0.f;
#pragma unroll
    for (int j = 0; j < NTOK; ++j) { float p = __expf(lg[j] - mx); lg[j] = p; sum += p; }
    float inv = 1.f / sum;

    float o[HD];
#pragma unroll
    for (int d = 0; d < HD; ++d) o[d] = 0.f;
#pragma unroll
    for (int j = 0; j < NTOK; ++j) {
      float p = lg[j];
#pragma unroll
      for (int d4 = 0; d4 < HD / 4; ++d4) {
        float4 kvec = ((const float4*)&kv[h][j * HD])[d4];
        o[d4 * 4 + 0] = fmaf(p, kvec.x, o[d4 * 4 + 0]);
        o[d4 * 4 + 1] = fmaf(p, kvec.y, o[d4 * 4 + 1]);
        o[d4 * 4 + 2] = fmaf(p, kvec.z, o[d4 * 4 + 2]);
        o[d4 * 4 + 3] = fmaf(p, kvec.w, o[d4 * 4 + 3]);
      }
    }
    float* O = attn_out + ((size_t)b * NTOK + l) * DIMC + h * HD;
#pragma unroll
    for (int d4 = 0; d4 < HD / 4; ++d4) {
      ((float4*)O)[d4] = make_float4(o[d4 * 4 + 0] * inv, o[d4 * 4 + 1] * inv,
                                     o[d4 * 4 + 2] * inv, o[d4 * 4 + 3] * inv);
    }
  }
}

extern "C" void kernel_launch(void* const* d_in, const int* in_sizes, int n_in,
                              void* d_out, int out_size, void* d_ws, size_t ws_size,
                              hipStream_t stream) {
  const float* x          = (const float*)d_in[0];
  const float* mask       = (const float*)d_in[1];
  const float* qkv_w      = (const float*)d_in[2];
  const float* qkv_b      = (const float*)d_in[3];
  const float* proj_w     = (const float*)d_in[4];
  const float* proj_b     = (const float*)d_in[5];
  const float* bias_table = (const float*)d_in[6];
  const int*   rel_index  = (const int*)d_in[7];
  float* out = (float*)d_out;

  __bf16* wpack = (__bf16*)d_ws;
  const __bf16* qwh = wpack;
  const __bf16* qwl = wpack + 49152;
  const __bf16* pwh = wpack + 98304;
  const __bf16* pwl = wpack + 98304 + 16384;
  float* bmT = (float*)((char*)d_ws + 262144);
  const size_t fixed_bytes = 262144 + 2458624;   // wpack + bmT

  int NC = 1;
  while (NC < 64 && (size_t)(B_ALL / NC) * 100352ull + fixed_bytes > ws_size) NC <<= 1;
  const int Bsl = B_ALL / NC;
  const int Msl = Bsl * NTOK;

  float* qkv_ws  = (float*)((char*)d_ws + fixed_bytes);            // (3,Bsl,4,49,32)
  float* attn_ws = qkv_ws + (size_t)3 * Bsl * NH * NTOK * HD;      // (Bsl,49,128)

  wpack_k<<<dim3(256), 256, 0, stream>>>(qkv_w, proj_w, wpack);
  bm_k<<<dim3(NWIN * NH * NTOK * NTOK / 256), 256, 0, stream>>>(mask, bias_table, rel_index, bmT);

  for (int sl = 0; sl < NC; ++sl) {
    const float* xs = x + (size_t)sl * Bsl * NTOK * DIMC;
    dim3 g1((Msl + 127) / 128, 3);
    mgemm_k<0><<<g1, 256, 0, stream>>>(xs, qwh, qwl, qkv_b, qkv_ws, Msl, Bsl);
    attn_k2<<<dim3(Bsl), 256, 0, stream>>>(qkv_ws, bmT, attn_ws, Bsl, sl * Bsl);
    dim3 g3((Msl + 127) / 128, 1);
    mgemm_k<1><<<g3, 256, 0, stream>>>(attn_ws, pwh, pwl, proj_b,
                                       out + (size_t)sl * Bsl * NTOK * DIMC, Msl, Bsl);
  }
}